// Round 1
// baseline (319.711 us; speedup 1.0000x reference)
//
#include <hip/hip_runtime.h>
#include <stdint.h>

typedef __attribute__((ext_vector_type(8))) short short8;
typedef __attribute__((ext_vector_type(4))) float f32x4;

#define NSIG   16
#define NPER   4096
#define DIN    256
#define DMODEL 1024
#define NB     16
#define NL     4096
#define LP1    4097

#define BM  128
#define BN  128
#define BK  64
#define LDK 72   // padded bf16 row stride (+8) -> 144B rows, 2-way bank alias (free)

// ---------------------------------------------------------------------------
// Fused: per-signal GEMM (bf16 MFMA) + scatter + metadata-add + mask
// grid = (65536/128) * (1024/128) = 4096 blocks, 256 threads (4 waves)
// ---------------------------------------------------------------------------
__global__ __launch_bounds__(256, 2)
void enc_gemm(const float* __restrict__ emb,
              const int* __restrict__ eidx,
              const int* __restrict__ pos,
              const int* __restrict__ sid,
              const int* __restrict__ mod_,
              const int* __restrict__ role,
              const unsigned char* __restrict__ pmask,
              const float* __restrict__ Wp,
              const float* __restrict__ bp,
              const float* __restrict__ pos_t,
              const float* __restrict__ id_t,
              const float* __restrict__ mod_t,
              const float* __restrict__ role_t,
              float* __restrict__ out)
{
    __shared__ unsigned short Ab[BM * LDK];
    __shared__ unsigned short Bb[BN * LDK];

    // XCD-chunked bijective swizzle (4096 blocks, 8 XCDs)
    const int bid = blockIdx.x;
    const int lg = (bid & 7) * 512 + (bid >> 3);
    const int rowBase = (lg >> 3) * BM;   // global row in [0, 65536)
    const int colBase = (lg & 7) * BN;    // col in [0, 1024)
    const int s = rowBase >> 12;          // signal id (128-row tile never crosses)

    const int t = threadIdx.x;
    const int lane = t & 63;
    const int w = t >> 6;
    const int wr = w >> 1, wc = w & 1;    // wave -> 64x64 quadrant

    f32x4 acc[4][4] = {};

    const int r0 = t >> 4;                // staging row within 16-row pass
    const int c4 = (t & 15) * 4;          // staging f32 col (float4)

    const float* Ag = emb + (size_t)rowBase * DIN;
    const float* Bg = Wp + ((size_t)s * DMODEL + colBase) * DIN;

    for (int kk = 0; kk < DIN; kk += BK) {
        // ---- stage A,B tiles: f32 -> bf16 (truncate), 8 passes of 16 rows ----
        #pragma unroll
        for (int p = 0; p < 8; ++p) {
            const int r = p * 16 + r0;
            const float4 va = *(const float4*)(Ag + (size_t)r * DIN + kk + c4);
            const float4 vb = *(const float4*)(Bg + (size_t)r * DIN + kk + c4);
            uint2 pa, pb;
            pa.x = (__builtin_bit_cast(uint32_t, va.x) >> 16) |
                   (__builtin_bit_cast(uint32_t, va.y) & 0xFFFF0000u);
            pa.y = (__builtin_bit_cast(uint32_t, va.z) >> 16) |
                   (__builtin_bit_cast(uint32_t, va.w) & 0xFFFF0000u);
            pb.x = (__builtin_bit_cast(uint32_t, vb.x) >> 16) |
                   (__builtin_bit_cast(uint32_t, vb.y) & 0xFFFF0000u);
            pb.y = (__builtin_bit_cast(uint32_t, vb.z) >> 16) |
                   (__builtin_bit_cast(uint32_t, vb.w) & 0xFFFF0000u);
            *(uint2*)&Ab[r * LDK + c4] = pa;
            *(uint2*)&Bb[r * LDK + c4] = pb;
        }
        __syncthreads();

        // ---- MFMA: 2 k-halves of 32, 4x4 fragments of 16x16 per wave ----
        #pragma unroll
        for (int h = 0; h < 2; ++h) {
            const int ko = h * 32 + (lane >> 4) * 8;
            short8 af[4], bf[4];
            #pragma unroll
            for (int m = 0; m < 4; ++m)
                af[m] = *(const short8*)&Ab[(wr * 64 + m * 16 + (lane & 15)) * LDK + ko];
            #pragma unroll
            for (int n = 0; n < 4; ++n)
                bf[n] = *(const short8*)&Bb[(wc * 64 + n * 16 + (lane & 15)) * LDK + ko];
            #pragma unroll
            for (int m = 0; m < 4; ++m) {
                #pragma unroll
                for (int n = 0; n < 4; ++n)
                    acc[m][n] = __builtin_amdgcn_mfma_f32_16x16x32_bf16(
                        af[m], bf[n], acc[m][n], 0, 0, 0);
            }
        }
        __syncthreads();
    }

    // ---- epilogue: bias + 4 table gathers + mask + scatter-store ----
    const int cb = colBase + wc * 64 + (lane & 15);
    float bpv[4];
    #pragma unroll
    for (int n = 0; n < 4; ++n) bpv[n] = bp[s * DMODEL + cb + n * 16];

    #pragma unroll
    for (int m = 0; m < 4; ++m) {
        #pragma unroll
        for (int j = 0; j < 4; ++j) {
            const int gr = rowBase + wr * 64 + m * 16 + (lane >> 4) * 4 + j;
            const int idx = eidx[gr];           // flat token slot (b*L + t)
            const int p_ = pos[idx];
            const int si = sid[idx];
            const int mo = mod_[idx];
            const int ro = role[idx];
            const int pm = pmask[idx];
            const size_t orow =
                ((size_t)(idx >> 12) * LP1 + 1 + (size_t)(idx & 4095)) * DMODEL;
            #pragma unroll
            for (int n = 0; n < 4; ++n) {
                const int col = cb + n * 16;
                float v = acc[m][n][j] + bpv[n]
                        + pos_t[(size_t)p_ * DMODEL + col]
                        + id_t[si * DMODEL + col]
                        + mod_t[mo * DMODEL + col]
                        + role_t[ro * DMODEL + col];
                v = pm ? 0.0f : v;
                __builtin_nontemporal_store(v, &out[orow + col]);
            }
        }
    }
}

// ---------------------------------------------------------------------------
// CLS rows + attn_keep
// ---------------------------------------------------------------------------
__global__ void enc_aux(const unsigned char* __restrict__ pmask,
                        const float* __restrict__ cls,
                        float* __restrict__ out)
{
    const size_t OUT_TOK = (size_t)NB * LP1 * DMODEL;
    const int i = blockIdx.x * blockDim.x + threadIdx.x;
    if (i < NB * LP1) {
        const int b = i / LP1;
        const int r = i - b * LP1;
        float keep = 1.0f;
        if (r > 0) keep = pmask[b * NL + r - 1] ? 0.0f : 1.0f;
        out[OUT_TOK + i] = keep;
    }
    if (i < NB * DMODEL) {
        const int b = i >> 10;
        const int e = i & (DMODEL - 1);
        out[(size_t)b * LP1 * DMODEL + e] = cls[e];
    }
}

extern "C" void kernel_launch(void* const* d_in, const int* in_sizes, int n_in,
                              void* d_out, int out_size, void* d_ws, size_t ws_size,
                              hipStream_t stream)
{
    (void)in_sizes; (void)n_in; (void)out_size; (void)d_ws; (void)ws_size;
    const float*         emb    = (const float*)d_in[0];
    const int*           eidx   = (const int*)d_in[1];
    const int*           pos    = (const int*)d_in[2];
    const int*           sid    = (const int*)d_in[3];
    const int*           mod_   = (const int*)d_in[4];
    const int*           role   = (const int*)d_in[5];
    const unsigned char* pmask  = (const unsigned char*)d_in[6];
    const float*         Wp     = (const float*)d_in[7];
    const float*         bp     = (const float*)d_in[8];
    const float*         cls    = (const float*)d_in[9];
    const float*         pos_t  = (const float*)d_in[10];
    const float*         id_t   = (const float*)d_in[11];
    const float*         mod_t  = (const float*)d_in[12];
    const float*         role_t = (const float*)d_in[13];
    float* out = (float*)d_out;

    enc_gemm<<<4096, 256, 0, stream>>>(emb, eidx, pos, sid, mod_, role, pmask,
                                       Wp, bp, pos_t, id_t, mod_t, role_t, out);

    const int naux = NB * LP1;  // 65552 >= NB*DMODEL
    enc_aux<<<(naux + 255) / 256, 256, 0, stream>>>(pmask, cls, out);
}

// Round 2
// 131.489 us; speedup vs baseline: 2.4315x; 2.4315x over previous
//
#include <hip/hip_runtime.h>
#include <stdint.h>

typedef __attribute__((ext_vector_type(8))) short short8;
typedef __attribute__((ext_vector_type(4))) float f32x4;
typedef unsigned short u16;
typedef unsigned int u32;

#define NSIG   16
#define NPER   4096
#define DIN    256
#define DMODEL 1024
#define NB     16
#define NL     4096
#define LP1    4097

// async global->LDS, 16B per lane, wave-uniform LDS base
#define GLDS(gp, lp) __builtin_amdgcn_global_load_lds( \
    (const __attribute__((address_space(1))) u32*)(const void*)(gp), \
    (__attribute__((address_space(3))) u32*)(void*)(lp), 16, 0, 0)

// ---------------------------------------------------------------------------
// f32 -> bf16 (truncate) conversion of emb and W_proj into workspace
// ---------------------------------------------------------------------------
__global__ __launch_bounds__(256)
void cvt_bf16(const float4* __restrict__ ea, const float4* __restrict__ wp,
              u16* __restrict__ wsA, u16* __restrict__ wsB)
{
    const int NA4 = NSIG * NPER * DIN / 4;   // 4,194,304
    const int NW4 = NSIG * DMODEL * DIN / 4; // 1,048,576
    int i = blockIdx.x * 256 + threadIdx.x;
    for (; i < NA4 + NW4; i += gridDim.x * 256) {
        const bool isA = i < NA4;
        const float4 v = isA ? ea[i] : wp[i - NA4];
        uint2 p;
        p.x = (__builtin_bit_cast(u32, v.x) >> 16) |
              (__builtin_bit_cast(u32, v.y) & 0xFFFF0000u);
        p.y = (__builtin_bit_cast(u32, v.z) >> 16) |
              (__builtin_bit_cast(u32, v.w) & 0xFFFF0000u);
        if (isA) *(uint2*)&wsA[(size_t)i * 4] = p;
        else     *(uint2*)&wsB[(size_t)(i - NA4) * 4] = p;
    }
}

// ---------------------------------------------------------------------------
// bf16 MFMA GEMM (global_load_lds staging, XOR-swizzled LDS) + fused epilogue
// grid = 4096 blocks x 256 threads
// ---------------------------------------------------------------------------
__global__ __launch_bounds__(256, 3)
void enc_gemm2(const u16* __restrict__ Abf,   // [65536][256] bf16
               const u16* __restrict__ Bbf,   // [16][1024][256] bf16
               const int* __restrict__ eidx,
               const int* __restrict__ pos,
               const int* __restrict__ sid,
               const int* __restrict__ mod_,
               const int* __restrict__ role,
               const unsigned char* __restrict__ pmask,
               const float* __restrict__ bp,
               const float* __restrict__ pos_t,
               const float* __restrict__ id_t,
               const float* __restrict__ mod_t,
               const float* __restrict__ role_t,
               float* __restrict__ out)
{
    __shared__ u16 Ab[128 * 64];   // 16 KB, rows of 64 bf16 (128 B)
    __shared__ u16 Bb[128 * 64];   // 16 KB

    // XCD-chunked bijective swizzle (4096 % 8 == 0)
    const int bid = blockIdx.x;
    const int lg = (bid & 7) * 512 + (bid >> 3);
    const int rowBase = (lg >> 3) * 128;
    const int colBase = (lg & 7) * 128;
    const int s = rowBase >> 12;

    const int t = threadIdx.x;
    const int lane = t & 63;
    const int w = t >> 6;
    const int wr = w >> 1, wc = w & 1;

    f32x4 acc[4][4] = {};

    // staging: lane -> (row-in-8, swizzled 16B chunk).  LDS dest is linear;
    // the SOURCE chunk is xor'd so that LDS[r][q] = global[r][q ^ (r&7)].
    const int srow = lane >> 3;                 // 0..7
    const int schunk = (lane & 7) ^ srow;       // source 16B-chunk within row
    const u16* Agbase = Abf + (size_t)rowBase * DIN;
    const u16* Bgbase = Bbf + ((size_t)s * DMODEL + colBase) * DIN;

    // fragment read: row r -> r&7 == lane&7 for all m (16/64 are mult. of 8)
    const int frow_a = wr * 64 + (lane & 15);
    const int frow_b = wc * 64 + (lane & 15);
    const int lxor = lane & 7;
    const int l4 = lane >> 4;

    for (int kk = 0; kk < DIN; kk += 64) {
        #pragma unroll
        for (int i = 0; i < 4; ++i) {
            const int c = w * 4 + i;            // 16 chunk-groups of 8 rows
            const int gr = c * 8 + srow;
            GLDS(Agbase + (size_t)gr * DIN + kk + schunk * 8, Ab + c * 512);
            GLDS(Bgbase + (size_t)gr * DIN + kk + schunk * 8, Bb + c * 512);
        }
        __syncthreads();

        #pragma unroll
        for (int h = 0; h < 2; ++h) {
            const int chunk = (h * 4 + l4) ^ lxor;  // swizzled read chunk
            short8 af[4], bf[4];
            #pragma unroll
            for (int m = 0; m < 4; ++m)
                af[m] = *(const short8*)&Ab[(frow_a + m * 16) * 64 + chunk * 8];
            #pragma unroll
            for (int n = 0; n < 4; ++n)
                bf[n] = *(const short8*)&Bb[(frow_b + n * 16) * 64 + chunk * 8];
            #pragma unroll
            for (int m = 0; m < 4; ++m) {
                #pragma unroll
                for (int n = 0; n < 4; ++n)
                    acc[m][n] = __builtin_amdgcn_mfma_f32_16x16x32_bf16(
                        af[m], bf[n], acc[m][n], 0, 0, 0);
            }
        }
        __syncthreads();
    }

    // ---- epilogue: bias + 4 table gathers + mask + scatter-store ----
    const int cb = colBase + wc * 64 + (lane & 15);
    float bpv[4];
    #pragma unroll
    for (int n = 0; n < 4; ++n) bpv[n] = bp[s * DMODEL + cb + n * 16];

    #pragma unroll
    for (int m = 0; m < 4; ++m) {
        #pragma unroll
        for (int j = 0; j < 4; ++j) {
            const int gr = rowBase + wr * 64 + m * 16 + (lane >> 4) * 4 + j;
            const int idx = eidx[gr];
            const int p_ = pos[idx];
            const int si = sid[idx];
            const int mo = mod_[idx];
            const int ro = role[idx];
            const int pm = pmask[idx];
            const size_t orow =
                ((size_t)(idx >> 12) * LP1 + 1 + (size_t)(idx & 4095)) * DMODEL;
            #pragma unroll
            for (int n = 0; n < 4; ++n) {
                const int col = cb + n * 16;
                float v = acc[m][n][j] + bpv[n]
                        + pos_t[(size_t)p_ * DMODEL + col]
                        + id_t[si * DMODEL + col]
                        + mod_t[mo * DMODEL + col]
                        + role_t[ro * DMODEL + col];
                v = pm ? 0.0f : v;
                __builtin_nontemporal_store(v, &out[orow + col]);
            }
        }
    }
}

// ---------------------------------------------------------------------------
// Fallback (round-1 kernel): fused f32->bf16 staging GEMM, used if ws too small
// ---------------------------------------------------------------------------
#define LDK 72
__global__ __launch_bounds__(256, 2)
void enc_gemm(const float* __restrict__ emb,
              const int* __restrict__ eidx,
              const int* __restrict__ pos,
              const int* __restrict__ sid,
              const int* __restrict__ mod_,
              const int* __restrict__ role,
              const unsigned char* __restrict__ pmask,
              const float* __restrict__ Wp,
              const float* __restrict__ bp,
              const float* __restrict__ pos_t,
              const float* __restrict__ id_t,
              const float* __restrict__ mod_t,
              const float* __restrict__ role_t,
              float* __restrict__ out)
{
    __shared__ u16 Ab[128 * LDK];
    __shared__ u16 Bb[128 * LDK];
    const int bid = blockIdx.x;
    const int lg = (bid & 7) * 512 + (bid >> 3);
    const int rowBase = (lg >> 3) * 128;
    const int colBase = (lg & 7) * 128;
    const int s = rowBase >> 12;
    const int t = threadIdx.x;
    const int lane = t & 63;
    const int w = t >> 6;
    const int wr = w >> 1, wc = w & 1;
    f32x4 acc[4][4] = {};
    const int r0 = t >> 4;
    const int c4 = (t & 15) * 4;
    const float* Ag = emb + (size_t)rowBase * DIN;
    const float* Bg = Wp + ((size_t)s * DMODEL + colBase) * DIN;
    for (int kk = 0; kk < DIN; kk += 64) {
        #pragma unroll
        for (int p = 0; p < 8; ++p) {
            const int r = p * 16 + r0;
            const float4 va = *(const float4*)(Ag + (size_t)r * DIN + kk + c4);
            const float4 vb = *(const float4*)(Bg + (size_t)r * DIN + kk + c4);
            uint2 pa, pb;
            pa.x = (__builtin_bit_cast(u32, va.x) >> 16) | (__builtin_bit_cast(u32, va.y) & 0xFFFF0000u);
            pa.y = (__builtin_bit_cast(u32, va.z) >> 16) | (__builtin_bit_cast(u32, va.w) & 0xFFFF0000u);
            pb.x = (__builtin_bit_cast(u32, vb.x) >> 16) | (__builtin_bit_cast(u32, vb.y) & 0xFFFF0000u);
            pb.y = (__builtin_bit_cast(u32, vb.z) >> 16) | (__builtin_bit_cast(u32, vb.w) & 0xFFFF0000u);
            *(uint2*)&Ab[r * LDK + c4] = pa;
            *(uint2*)&Bb[r * LDK + c4] = pb;
        }
        __syncthreads();
        #pragma unroll
        for (int h = 0; h < 2; ++h) {
            const int ko = h * 32 + (lane >> 4) * 8;
            short8 af[4], bf[4];
            #pragma unroll
            for (int m = 0; m < 4; ++m)
                af[m] = *(const short8*)&Ab[(wr * 64 + m * 16 + (lane & 15)) * LDK + ko];
            #pragma unroll
            for (int n = 0; n < 4; ++n)
                bf[n] = *(const short8*)&Bb[(wc * 64 + n * 16 + (lane & 15)) * LDK + ko];
            #pragma unroll
            for (int m = 0; m < 4; ++m) {
                #pragma unroll
                for (int n = 0; n < 4; ++n)
                    acc[m][n] = __builtin_amdgcn_mfma_f32_16x16x32_bf16(af[m], bf[n], acc[m][n], 0, 0, 0);
            }
        }
        __syncthreads();
    }
    const int cb = colBase + wc * 64 + (lane & 15);
    float bpv[4];
    #pragma unroll
    for (int n = 0; n < 4; ++n) bpv[n] = bp[s * DMODEL + cb + n * 16];
    #pragma unroll
    for (int m = 0; m < 4; ++m) {
        #pragma unroll
        for (int j = 0; j < 4; ++j) {
            const int gr = rowBase + wr * 64 + m * 16 + (lane >> 4) * 4 + j;
            const int idx = eidx[gr];
            const int p_ = pos[idx];
            const int si = sid[idx];
            const int mo = mod_[idx];
            const int ro = role[idx];
            const int pm = pmask[idx];
            const size_t orow = ((size_t)(idx >> 12) * LP1 + 1 + (size_t)(idx & 4095)) * DMODEL;
            #pragma unroll
            for (int n = 0; n < 4; ++n) {
                const int col = cb + n * 16;
                float v = acc[m][n][j] + bpv[n]
                        + pos_t[(size_t)p_ * DMODEL + col]
                        + id_t[si * DMODEL + col]
                        + mod_t[mo * DMODEL + col]
                        + role_t[ro * DMODEL + col];
                v = pm ? 0.0f : v;
                __builtin_nontemporal_store(v, &out[orow + col]);
            }
        }
    }
}

// ---------------------------------------------------------------------------
// CLS rows + attn_keep
// ---------------------------------------------------------------------------
__global__ void enc_aux(const unsigned char* __restrict__ pmask,
                        const float* __restrict__ cls,
                        float* __restrict__ out)
{
    const size_t OUT_TOK = (size_t)NB * LP1 * DMODEL;
    const int i = blockIdx.x * blockDim.x + threadIdx.x;
    if (i < NB * LP1) {
        const int b = i / LP1;
        const int r = i - b * LP1;
        float keep = 1.0f;
        if (r > 0) keep = pmask[b * NL + r - 1] ? 0.0f : 1.0f;
        out[OUT_TOK + i] = keep;
    }
    if (i < NB * DMODEL) {
        const int b = i >> 10;
        const int e = i & (DMODEL - 1);
        out[(size_t)b * LP1 * DMODEL + e] = cls[e];
    }
}

extern "C" void kernel_launch(void* const* d_in, const int* in_sizes, int n_in,
                              void* d_out, int out_size, void* d_ws, size_t ws_size,
                              hipStream_t stream)
{
    (void)in_sizes; (void)n_in; (void)out_size;
    const float*         emb    = (const float*)d_in[0];
    const int*           eidx   = (const int*)d_in[1];
    const int*           pos    = (const int*)d_in[2];
    const int*           sid    = (const int*)d_in[3];
    const int*           mod_   = (const int*)d_in[4];
    const int*           role   = (const int*)d_in[5];
    const unsigned char* pmask  = (const unsigned char*)d_in[6];
    const float*         Wp     = (const float*)d_in[7];
    const float*         bp     = (const float*)d_in[8];
    const float*         cls    = (const float*)d_in[9];
    const float*         pos_t  = (const float*)d_in[10];
    const float*         id_t   = (const float*)d_in[11];
    const float*         mod_t  = (const float*)d_in[12];
    const float*         role_t = (const float*)d_in[13];
    float* out = (float*)d_out;

    const size_t WS_NEED = ((size_t)NSIG * NPER * DIN + (size_t)NSIG * DMODEL * DIN) * 2;
    if (ws_size >= WS_NEED) {
        u16* wsA = (u16*)d_ws;                       // 65536 x 256 bf16
        u16* wsB = wsA + (size_t)NSIG * NPER * DIN;  // 16 x 1024 x 256 bf16
        cvt_bf16<<<2048, 256, 0, stream>>>((const float4*)emb, (const float4*)Wp, wsA, wsB);
        enc_gemm2<<<4096, 256, 0, stream>>>(wsA, wsB, eidx, pos, sid, mod_, role, pmask,
                                            bp, pos_t, id_t, mod_t, role_t, out);
    } else {
        enc_gemm<<<4096, 256, 0, stream>>>(emb, eidx, pos, sid, mod_, role, pmask,
                                           Wp, bp, pos_t, id_t, mod_t, role_t, out);
    }

    const int naux = NB * LP1;
    enc_aux<<<(naux + 255) / 256, 256, 0, stream>>>(pmask, cls, out);
}

// Round 4
// 129.200 us; speedup vs baseline: 2.4746x; 1.0177x over previous
//
#include <hip/hip_runtime.h>
#include <stdint.h>

typedef __attribute__((ext_vector_type(8))) short short8;
typedef __attribute__((ext_vector_type(4))) float f32x4;
typedef unsigned short u16;
typedef unsigned int u32;

#define NSIG   16
#define NPER   4096
#define DIN    256
#define DMODEL 1024
#define NB     16
#define NL     4096
#define LP1    4097
#define LDK    72   // padded bf16 row stride (144 B) -> ~2-way bank alias (free)

// ---------------------------------------------------------------------------
// Fused: f32 -> reg prefetch -> bf16 padded-LDS -> MFMA GEMM -> scatter +
// metadata gathers + mask.  grid = 4096 x 256.  All staging/compute/epilogue
// math identical to the round-1/2 kernels that passed; only the software
// pipeline (reg double-buffer of the next k-tile) is new.
// ---------------------------------------------------------------------------
__global__ __launch_bounds__(256, 2)
void enc_fused(const float* __restrict__ emb,     // [65536][256] f32
               const int* __restrict__ eidx,
               const int* __restrict__ pos,
               const int* __restrict__ sid,
               const int* __restrict__ mod_,
               const int* __restrict__ role,
               const unsigned char* __restrict__ pmask,
               const float* __restrict__ Wp,      // [16][1024][256] f32
               const float* __restrict__ bp,
               const float* __restrict__ pos_t,
               const float* __restrict__ id_t,
               const float* __restrict__ mod_t,
               const float* __restrict__ role_t,
               float* __restrict__ out)
{
    __shared__ u16 Ab[128 * LDK];   // 18 KB
    __shared__ u16 Bb[128 * LDK];   // 18 KB

    // XCD-chunked bijective swizzle (4096 % 8 == 0)
    const int bid = blockIdx.x;
    const int lg = (bid & 7) * 512 + (bid >> 3);
    const int rowBase = (lg >> 3) * 128;
    const int colBase = (lg & 7) * 128;
    const int s = rowBase >> 12;

    const int t = threadIdx.x;
    const int lane = t & 63;
    const int w = t >> 6;
    const int wr = w >> 1, wc = w & 1;

    f32x4 acc[4][4] = {};

    const int r0 = t >> 4;          // staging row within 16-row pass
    const int c4 = (t & 15) * 4;    // staging f32 col (float4)

    const float* Ag = emb + (size_t)rowBase * DIN;
    const float* Bg = Wp + ((size_t)s * DMODEL + colBase) * DIN;

    // ---- prologue: k-tile 0 into registers ----
    float4 rA[8], rB[8];
    #pragma unroll
    for (int p = 0; p < 8; ++p) {
        const int r = p * 16 + r0;
        rA[p] = *(const float4*)(Ag + (size_t)r * DIN + c4);
        rB[p] = *(const float4*)(Bg + (size_t)r * DIN + c4);
    }

    for (int kk = 0; kk < DIN; kk += 64) {
        // ---- pack current regs -> LDS (round-1 proven math) ----
        #pragma unroll
        for (int p = 0; p < 8; ++p) {
            const int r = p * 16 + r0;
            const float4 va = rA[p];
            const float4 vb = rB[p];
            uint2 pa, pb;
            pa.x = (__builtin_bit_cast(u32, va.x) >> 16) | (__builtin_bit_cast(u32, va.y) & 0xFFFF0000u);
            pa.y = (__builtin_bit_cast(u32, va.z) >> 16) | (__builtin_bit_cast(u32, va.w) & 0xFFFF0000u);
            pb.x = (__builtin_bit_cast(u32, vb.x) >> 16) | (__builtin_bit_cast(u32, vb.y) & 0xFFFF0000u);
            pb.y = (__builtin_bit_cast(u32, vb.z) >> 16) | (__builtin_bit_cast(u32, vb.w) & 0xFFFF0000u);
            *(uint2*)&Ab[r * LDK + c4] = pa;
            *(uint2*)&Bb[r * LDK + c4] = pb;
        }
        __syncthreads();

        // ---- issue next k-tile loads (latency hides under MFMA below) ----
        if (kk + 64 < DIN) {
            #pragma unroll
            for (int p = 0; p < 8; ++p) {
                const int r = p * 16 + r0;
                rA[p] = *(const float4*)(Ag + (size_t)r * DIN + kk + 64 + c4);
                rB[p] = *(const float4*)(Bg + (size_t)r * DIN + kk + 64 + c4);
            }
        }

        // ---- MFMA (round-1/2 proven pattern) ----
        #pragma unroll
        for (int h = 0; h < 2; ++h) {
            const int ko = h * 32 + (lane >> 4) * 8;
            short8 af[4], bf[4];
            #pragma unroll
            for (int m = 0; m < 4; ++m)
                af[m] = *(const short8*)&Ab[(wr * 64 + m * 16 + (lane & 15)) * LDK + ko];
            #pragma unroll
            for (int n = 0; n < 4; ++n)
                bf[n] = *(const short8*)&Bb[(wc * 64 + n * 16 + (lane & 15)) * LDK + ko];
            #pragma unroll
            for (int m = 0; m < 4; ++m) {
                #pragma unroll
                for (int n = 0; n < 4; ++n)
                    acc[m][n] = __builtin_amdgcn_mfma_f32_16x16x32_bf16(
                        af[m], bf[n], acc[m][n], 0, 0, 0);
            }
        }
        __syncthreads();
    }

    // ---- epilogue (round-1/2 verbatim): bias + 4 gathers + mask + scatter ----
    const int cb = colBase + wc * 64 + (lane & 15);
    float bpv[4];
    #pragma unroll
    for (int n = 0; n < 4; ++n) bpv[n] = bp[s * DMODEL + cb + n * 16];

    #pragma unroll
    for (int m = 0; m < 4; ++m) {
        #pragma unroll
        for (int j = 0; j < 4; ++j) {
            const int gr = rowBase + wr * 64 + m * 16 + (lane >> 4) * 4 + j;
            const int idx = eidx[gr];
            const int p_ = pos[idx];
            const int si = sid[idx];
            const int mo = mod_[idx];
            const int ro = role[idx];
            const int pm = pmask[idx];
            const size_t orow =
                ((size_t)(idx >> 12) * LP1 + 1 + (size_t)(idx & 4095)) * DMODEL;
            #pragma unroll
            for (int n = 0; n < 4; ++n) {
                const int col = cb + n * 16;
                float v = acc[m][n][j] + bpv[n]
                        + pos_t[(size_t)p_ * DMODEL + col]
                        + id_t[si * DMODEL + col]
                        + mod_t[mo * DMODEL + col]
                        + role_t[ro * DMODEL + col];
                v = pm ? 0.0f : v;
                __builtin_nontemporal_store(v, &out[orow + col]);
            }
        }
    }
}

// ---------------------------------------------------------------------------
// CLS rows + attn_keep
// ---------------------------------------------------------------------------
__global__ void enc_aux(const unsigned char* __restrict__ pmask,
                        const float* __restrict__ cls,
                        float* __restrict__ out)
{
    const size_t OUT_TOK = (size_t)NB * LP1 * DMODEL;
    const int i = blockIdx.x * blockDim.x + threadIdx.x;
    if (i < NB * LP1) {
        const int b = i / LP1;
        const int r = i - b * LP1;
        float keep = 1.0f;
        if (r > 0) keep = pmask[b * NL + r - 1] ? 0.0f : 1.0f;
        out[OUT_TOK + i] = keep;
    }
    if (i < NB * DMODEL) {
        const int b = i >> 10;
        const int e = i & (DMODEL - 1);
        out[(size_t)b * LP1 * DMODEL + e] = cls[e];
    }
}

extern "C" void kernel_launch(void* const* d_in, const int* in_sizes, int n_in,
                              void* d_out, int out_size, void* d_ws, size_t ws_size,
                              hipStream_t stream)
{
    (void)in_sizes; (void)n_in; (void)out_size; (void)d_ws; (void)ws_size;
    const float*         emb    = (const float*)d_in[0];
    const int*           eidx   = (const int*)d_in[1];
    const int*           pos    = (const int*)d_in[2];
    const int*           sid    = (const int*)d_in[3];
    const int*           mod_   = (const int*)d_in[4];
    const int*           role   = (const int*)d_in[5];
    const unsigned char* pmask  = (const unsigned char*)d_in[6];
    const float*         Wp     = (const float*)d_in[7];
    const float*         bp     = (const float*)d_in[8];
    const float*         cls    = (const float*)d_in[9];
    const float*         pos_t  = (const float*)d_in[10];
    const float*         id_t   = (const float*)d_in[11];
    const float*         mod_t  = (const float*)d_in[12];
    const float*         role_t = (const float*)d_in[13];
    float* out = (float*)d_out;

    enc_fused<<<4096, 256, 0, stream>>>(emb, eidx, pos, sid, mod_, role, pmask,
                                        Wp, bp, pos_t, id_t, mod_t, role_t, out);

    const int naux = NB * LP1;
    enc_aux<<<(naux + 255) / 256, 256, 0, stream>>>(pmask, cls, out);
}